// Round 1
// baseline (794.916 us; speedup 1.0000x reference)
//
#include <hip/hip_runtime.h>
#include <math.h>

#define NS 65536
#define LAN 2048
#define FEA 128

constexpr float THRES = 0.0025f;
constexpr float FEPS  = 1e-12f;
constexpr int BM   = 16;
constexpr int MAXS = 400;   // hard bound: #survivors < 1/THRES = 400

// ---------------- kernel A: transpose W [2048][128] -> Wt [128][2048] ----------------
__global__ void k_transpose(const float* __restrict__ W, float* __restrict__ Wt) {
    int c = blockIdx.x;          // 0..2047
    int k = threadIdx.x;         // 0..127
    Wt[(size_t)k * LAN + c] = W[(size_t)c * FEA + k];
}

// ---------------- kernel B: cen[k] = mean_c W[c][k]  (from Wt rows, coalesced) -------
__global__ void k_cen(const float* __restrict__ Wt, float* __restrict__ cen) {
    __shared__ float sb[4];
    int k = blockIdx.x;          // 0..127
    int tid = threadIdx.x;       // 256
    float s = 0.f;
    for (int c = tid; c < LAN; c += 256) s += Wt[(size_t)k * LAN + c];
    #pragma unroll
    for (int off = 32; off >= 1; off >>= 1) s += __shfl_xor(s, off);
    if ((tid & 63) == 0) sb[tid >> 6] = s;
    __syncthreads();
    if (tid == 0) cen[k] = (sb[0] + sb[1] + sb[2] + sb[3]) * (1.0f / (float)LAN);
}

// ---------------- main fused kernel ----------------
// grid = NS/BM blocks, 256 threads. Thread tile: 8 rows x 16 cols (4 strided float4s).
__global__ __launch_bounds__(256, 2) void k_main(
    const float* __restrict__ X, const float* __restrict__ W,
    const float* __restrict__ Wt, const float* __restrict__ cen,
    float* __restrict__ o_out, float* __restrict__ o_att,
    float* __restrict__ o_nl, float* __restrict__ o_nl2,
    float* __restrict__ o_col)
{
    __shared__ __align__(16) float xs[FEA][BM + 4];    // [k][r], pad to 20 floats (16B-aligned rows)
    __shared__ __align__(16) char  ubuf[8 * LAN * 4];  // 64 KB: W k-slice, then survivor lists
    __shared__ float s_red[4][8];
    __shared__ int   s_redi[4][8];
    __shared__ int   s_ind[BM], s_ind2[BM], s_cnt[BM];

    float4* ws4 = (float4*)ubuf;

    const int tid  = threadIdx.x;
    const int lane = tid & 63;
    const int wv   = tid >> 6;    // wave 0..3
    const int rg   = tid >> 7;    // row group 0..1 (8 rows each)
    const int cg   = tid & 127;   // col group 0..127
    const int row0 = blockIdx.x * BM;
    const int rbase = rg * 8;

    // ---- stage x tile transposed: xs[k][r] = X[row0+r][k] ----
    #pragma unroll
    for (int q = 0; q < 8; ++q) {
        int f = tid * 8 + q;              // 0..2047
        int r = f >> 7;
        int k = f & 127;
        xs[k][r] = X[(size_t)(row0 + r) * FEA + k];
    }

    // ---- GEMM: logits[r][c] for r in rg*8..+7, c in {4cg+512j+i} ----
    float acc[8][16];
    #pragma unroll
    for (int r = 0; r < 8; ++r)
        #pragma unroll
        for (int e = 0; e < 16; ++e) acc[r][e] = 0.f;

    for (int step = 0; step < 16; ++step) {
        __syncthreads();   // previous slice consumers done
        const float4* src = (const float4*)(Wt + (size_t)step * 8 * LAN);
        #pragma unroll
        for (int q = 0; q < 16; ++q) ws4[tid + 256 * q] = src[tid + 256 * q];
        __syncthreads();
        const int kb = step * 8;
        #pragma unroll
        for (int k = 0; k < 8; ++k) {
            // a-frag: 8 consecutive row values (wave-uniform broadcast reads)
            float4 a01 = *(const float4*)&xs[kb + k][rbase];
            float4 a23 = *(const float4*)&xs[kb + k][rbase + 4];
            float a[8] = {a01.x, a01.y, a01.z, a01.w, a23.x, a23.y, a23.z, a23.w};
            // b-frag: 4 strided float4s, lane-consecutive 16B (conflict-free)
            float4 b0 = ws4[k * 512 + cg];
            float4 b1 = ws4[k * 512 + cg + 128];
            float4 b2 = ws4[k * 512 + cg + 256];
            float4 b3 = ws4[k * 512 + cg + 384];
            #pragma unroll
            for (int r = 0; r < 8; ++r) {
                acc[r][0]  += a[r] * b0.x;  acc[r][1]  += a[r] * b0.y;
                acc[r][2]  += a[r] * b0.z;  acc[r][3]  += a[r] * b0.w;
                acc[r][4]  += a[r] * b1.x;  acc[r][5]  += a[r] * b1.y;
                acc[r][6]  += a[r] * b1.z;  acc[r][7]  += a[r] * b1.w;
                acc[r][8]  += a[r] * b2.x;  acc[r][9]  += a[r] * b2.y;
                acc[r][10] += a[r] * b2.z;  acc[r][11] += a[r] * b2.w;
                acc[r][12] += a[r] * b3.x;  acc[r][13] += a[r] * b3.y;
                acc[r][14] += a[r] * b3.z;  acc[r][15] += a[r] * b3.w;
            }
        }
    }
    __syncthreads();   // GEMM done; ubuf free for reuse after this point

    // ---- row max ----
    float rmax[8], rsum[8], Ssum[8];
    {
        float pm[8];
        #pragma unroll
        for (int r = 0; r < 8; ++r) {
            float m = acc[r][0];
            #pragma unroll
            for (int e = 1; e < 16; ++e) m = fmaxf(m, acc[r][e]);
            #pragma unroll
            for (int off = 32; off >= 1; off >>= 1) m = fmaxf(m, __shfl_xor(m, off));
            pm[r] = m;
        }
        if (lane == 0)
            #pragma unroll
            for (int r = 0; r < 8; ++r) s_red[wv][r] = pm[r];
        __syncthreads();
        #pragma unroll
        for (int r = 0; r < 8; ++r) rmax[r] = fmaxf(s_red[2*rg][r], s_red[2*rg+1][r]);
        __syncthreads();
    }
    // ---- sum of exp (overwrite acc with exp) ----
    {
        #pragma unroll
        for (int r = 0; r < 8; ++r) {
            float s = 0.f;
            #pragma unroll
            for (int e = 0; e < 16; ++e) {
                float v = expf(acc[r][e] - rmax[r]);
                acc[r][e] = v; s += v;
            }
            #pragma unroll
            for (int off = 32; off >= 1; off >>= 1) s += __shfl_xor(s, off);
            if (lane == 0) s_red[wv][r] = s;
        }
        __syncthreads();
        #pragma unroll
        for (int r = 0; r < 8; ++r) rsum[r] = s_red[2*rg][r] + s_red[2*rg+1][r];
        __syncthreads();
    }
    // ---- shrink (overwrite acc with shrunk), S = sum ----
    {
        #pragma unroll
        for (int r = 0; r < 8; ++r) {
            float s = 0.f;
            #pragma unroll
            for (int e = 0; e < 16; ++e) {
                float soft = acc[r][e] / rsum[r];
                float sh = soft - THRES;
                float v = (sh > 0.f) ? (sh * soft) / (sh + FEPS) : 0.f;
                acc[r][e] = v; s += v;
            }
            #pragma unroll
            for (int off = 32; off >= 1; off >>= 1) s += __shfl_xor(s, off);
            if (lane == 0) s_red[wv][r] = s;
        }
        __syncthreads();
        #pragma unroll
        for (int r = 0; r < 8; ++r) Ssum[r] = s_red[2*rg][r] + s_red[2*rg+1][r];
        if (tid < BM) s_cnt[tid] = 0;
        __syncthreads();
    }

    // ---- normalize, write att, scatter survivors, argmax partials ----
    int*   scols = (int*)ubuf;
    float* svals = (float*)(ubuf + BM * MAXS * sizeof(int));
    float bv[8]; int bc[8];
    #pragma unroll
    for (int r = 0; r < 8; ++r) {
        bv[r] = -1.f; bc[r] = 0x7fffffff;
        const int lr = rbase + r;
        const float den = fmaxf(Ssum[r], FEPS);
        const size_t rowoff = (size_t)(row0 + lr) * LAN;
        #pragma unroll
        for (int j = 0; j < 4; ++j) {
            const int c0 = 4 * cg + 512 * j;
            float v0 = acc[r][4*j+0] / den;
            float v1 = acc[r][4*j+1] / den;
            float v2 = acc[r][4*j+2] / den;
            float v3 = acc[r][4*j+3] / den;
            acc[r][4*j+0] = v0; acc[r][4*j+1] = v1;   // keep normalized for ind2 pass
            acc[r][4*j+2] = v2; acc[r][4*j+3] = v3;
            *(float4*)(o_att + rowoff + c0) = make_float4(v0, v1, v2, v3);
            // in-thread scan is in increasing c order -> strict '>' keeps first index
            if (v0 > bv[r]) { bv[r] = v0; bc[r] = c0; }
            if (v1 > bv[r]) { bv[r] = v1; bc[r] = c0 + 1; }
            if (v2 > bv[r]) { bv[r] = v2; bc[r] = c0 + 2; }
            if (v3 > bv[r]) { bv[r] = v3; bc[r] = c0 + 3; }
            if (v0 > 0.f) { int p = atomicAdd(&s_cnt[lr], 1); if (p < MAXS) { scols[lr*MAXS+p] = c0;   svals[lr*MAXS+p] = v0; } }
            if (v1 > 0.f) { int p = atomicAdd(&s_cnt[lr], 1); if (p < MAXS) { scols[lr*MAXS+p] = c0+1; svals[lr*MAXS+p] = v1; } }
            if (v2 > 0.f) { int p = atomicAdd(&s_cnt[lr], 1); if (p < MAXS) { scols[lr*MAXS+p] = c0+2; svals[lr*MAXS+p] = v2; } }
            if (v3 > 0.f) { int p = atomicAdd(&s_cnt[lr], 1); if (p < MAXS) { scols[lr*MAXS+p] = c0+3; svals[lr*MAXS+p] = v3; } }
        }
    }
    // ---- argmax reduce -> s_ind ----
    #pragma unroll
    for (int r = 0; r < 8; ++r) {
        float v = bv[r]; int c = bc[r];
        #pragma unroll
        for (int off = 32; off >= 1; off >>= 1) {
            float ov = __shfl_xor(v, off); int oc = __shfl_xor(c, off);
            if (ov > v || (ov == v && oc < c)) { v = ov; c = oc; }
        }
        if (lane == 0) { s_red[wv][r] = v; s_redi[wv][r] = c; }
    }
    __syncthreads();
    if (cg == 0) {
        #pragma unroll
        for (int r = 0; r < 8; ++r) {
            float va = s_red[2*rg][r];   int ca = s_redi[2*rg][r];
            float vb = s_red[2*rg+1][r]; int cb = s_redi[2*rg+1][r];
            s_ind[rbase + r] = (vb > va || (vb == va && cb < ca)) ? cb : ca;
        }
    }
    __syncthreads();
    // ---- second argmax (value at ind treated as row_min == 0) -> s_ind2 ----
    #pragma unroll
    for (int r = 0; r < 8; ++r) {
        const int ind = s_ind[rbase + r];
        float v = -1.f; int c = 0x7fffffff;
        #pragma unroll
        for (int j = 0; j < 4; ++j) {
            #pragma unroll
            for (int i = 0; i < 4; ++i) {
                int cc = 4 * cg + 512 * j + i;
                float vv = acc[r][4*j+i];
                if (cc == ind) vv = 0.f;
                if (vv > v || (vv == v && cc < c)) { v = vv; c = cc; }
            }
        }
        #pragma unroll
        for (int off = 32; off >= 1; off >>= 1) {
            float ov = __shfl_xor(v, off); int oc = __shfl_xor(c, off);
            if (ov > v || (ov == v && oc < c)) { v = ov; c = oc; }
        }
        if (lane == 0) { s_red[wv][r] = v; s_redi[wv][r] = c; }
    }
    __syncthreads();
    if (cg == 0) {
        #pragma unroll
        for (int r = 0; r < 8; ++r) {
            float va = s_red[2*rg][r];   int ca = s_redi[2*rg][r];
            float vb = s_red[2*rg+1][r]; int cb = s_redi[2*rg+1][r];
            s_ind2[rbase + r] = (vb > va || (vb == va && cb < ca)) ? cb : ca;
        }
    }
    __syncthreads();

    // ---- per-row finals: sparse att@W, nl, nl2, col. wave wv handles rows 4wv..4wv+3 ----
    for (int t = 0; t < 4; ++t) {
        const int lr = wv * 4 + t;
        const int grow = row0 + lr;
        const int d0 = lane * 2;
        float o0 = 0.f, o1 = 0.f;
        const int cnt = min(s_cnt[lr], MAXS);
        for (int s2 = 0; s2 < cnt; ++s2) {
            const int c = scols[lr * MAXS + s2];
            const float v = svals[lr * MAXS + s2];
            const float2 w2 = *(const float2*)(W + (size_t)c * FEA + d0);
            o0 += v * w2.x; o1 += v * w2.y;
        }
        *(float2*)(o_out + (size_t)grow * FEA + d0) = make_float2(o0, o1);
        const int i1 = s_ind[lr], i2 = s_ind2[lr];
        *(float2*)(o_nl  + (size_t)grow * FEA + d0) = *(const float2*)(W + (size_t)i1 * FEA + d0);
        *(float2*)(o_nl2 + (size_t)grow * FEA + d0) = *(const float2*)(W + (size_t)i2 * FEA + d0);
        float dx0 = xs[d0][lr]     - cen[d0];
        float dx1 = xs[d0 + 1][lr] - cen[d0 + 1];
        float dd = dx0 * dx0 + dx1 * dx1;
        #pragma unroll
        for (int off = 32; off >= 1; off >>= 1) dd += __shfl_xor(dd, off);
        if (lane == 0) o_col[grow] = (sqrtf(dd) < 1.0f) ? 1.0f : 0.0f;
    }
}

extern "C" void kernel_launch(void* const* d_in, const int* in_sizes, int n_in,
                              void* d_out, int out_size, void* d_ws, size_t ws_size,
                              hipStream_t stream) {
    const float* X = (const float*)d_in[0];
    const float* W = (const float*)d_in[1];
    float* Wt  = (float*)d_ws;                 // 128*2048 floats = 1 MB
    float* cen = (float*)d_ws + (size_t)FEA * LAN;  // +512 B

    float* out      = (float*)d_out;
    float* o_output = out;
    float* o_att    = o_output + (size_t)NS * FEA;
    float* o_nl     = o_att    + (size_t)NS * LAN;
    float* o_nl2    = o_nl     + (size_t)NS * FEA;
    float* o_col    = o_nl2    + (size_t)NS * FEA;

    k_transpose<<<LAN, FEA, 0, stream>>>(W, Wt);
    k_cen<<<FEA, 256, 0, stream>>>(Wt, cen);
    k_main<<<NS / BM, 256, 0, stream>>>(X, W, Wt, cen,
                                        o_output, o_att, o_nl, o_nl2, o_col);
}